// Round 1
// baseline (271.858 us; speedup 1.0000x reference)
//
#include <hip/hip_runtime.h>

// Problem constants
#define NTOK   2048      // 2 * 1024 tokens
#define DIM    64
#define NCODES 50000
#define NCHUNK 32
#define CHUNK  1563      // ceil(50000/32)
#define MT     128       // token tile
#define NT     128       // code tile
#define TILES_PER_CHUNK 13  // ceil(1563/128)
#define THRESH 100.0f
#define BIG    3.0e38f

// ---------------------------------------------------------------------------
// Kernel 1: squared norms of codes (c2) and tokens (x2).
// Threads 0..49999 -> c2; threads 0..2047 additionally -> x2.
// ---------------------------------------------------------------------------
__global__ void nn_norms_kernel(const float* __restrict__ x,
                                const float* __restrict__ codes,
                                float* __restrict__ c2,
                                float* __restrict__ x2) {
    int gid = blockIdx.x * 256 + threadIdx.x;
    if (gid < NCODES) {
        const float4* p = (const float4*)(codes + (size_t)gid * DIM);
        float s = 0.f;
#pragma unroll
        for (int i = 0; i < DIM / 4; ++i) {
            float4 v = p[i];
            s = fmaf(v.x, v.x, s); s = fmaf(v.y, v.y, s);
            s = fmaf(v.z, v.z, s); s = fmaf(v.w, v.w, s);
        }
        c2[gid] = s;
    }
    if (gid < NTOK) {
        const float4* p = (const float4*)(x + (size_t)gid * DIM);
        float s = 0.f;
#pragma unroll
        for (int i = 0; i < DIM / 4; ++i) {
            float4 v = p[i];
            s = fmaf(v.x, v.x, s); s = fmaf(v.y, v.y, s);
            s = fmaf(v.z, v.z, s); s = fmaf(v.w, v.w, s);
        }
        x2[gid] = s;
    }
}

// ---------------------------------------------------------------------------
// Kernel 2: per (token-tile, code-chunk) partial argmin.
// Block = 256 threads as 16(tx: codes) x 16(ty: tokens), 8x8 micro-tile each.
// LDS tiles stored k-major: xs[k][m], cs[k][n] so the inner loop reads
// contiguous float4 fragments per k.
// ---------------------------------------------------------------------------
__global__ __launch_bounds__(256, 2)
void nn_stage1_kernel(const float* __restrict__ x,
                      const float* __restrict__ codes,
                      const float* __restrict__ c2g,
                      const float* __restrict__ x2g,
                      float* __restrict__ pmin,
                      int* __restrict__ pidx) {
    // xs: 64*128 floats (32KB), cs: 64*128 (32KB), c2s: 128  -> ~66KB
    __shared__ float smem[DIM * MT + DIM * NT + NT];
    float* xs  = smem;                 // [64][128]
    float* cs  = smem + DIM * MT;      // [64][128]
    float* c2s = smem + DIM * (MT + NT); // [128]

    const int tid = threadIdx.x;
    const int tx = tid & 15;   // code column group
    const int ty = tid >> 4;   // token row group
    const int m0 = blockIdx.x * MT;
    const int chunk = blockIdx.y;
    const int cstart = chunk * CHUNK;
    const int cend = min(cstart + CHUNK, NCODES);

    // Stage x tile transposed: xs[k][m]. idx -> m = idx>>4, k4 = (idx&15)*4
#pragma unroll
    for (int it = 0; it < (MT * DIM / 4) / 256; ++it) {
        int idx = it * 256 + tid;
        int m = idx >> 4;
        int k4 = (idx & 15) * 4;
        float4 v = *(const float4*)(x + (size_t)(m0 + m) * DIM + k4);
        xs[(k4 + 0) * MT + m] = v.x;
        xs[(k4 + 1) * MT + m] = v.y;
        xs[(k4 + 2) * MT + m] = v.z;
        xs[(k4 + 3) * MT + m] = v.w;
    }

    float bmin[8];
    int   bidx[8];
#pragma unroll
    for (int i = 0; i < 8; ++i) { bmin[i] = BIG; bidx[i] = 0; }

    for (int t = 0; t < TILES_PER_CHUNK; ++t) {
        const int nbase = cstart + t * NT;
        __syncthreads();  // protect cs/c2s from previous iteration's readers

        // Stage code tile transposed: cs[k][n]; zero-fill out-of-range codes.
#pragma unroll
        for (int it = 0; it < (NT * DIM / 4) / 256; ++it) {
            int idx = it * 256 + tid;
            int n = idx >> 4;
            int k4 = (idx & 15) * 4;
            int gn = nbase + n;
            float4 v = make_float4(0.f, 0.f, 0.f, 0.f);
            if (gn < cend) v = *(const float4*)(codes + (size_t)gn * DIM + k4);
            cs[(k4 + 0) * NT + n] = v.x;
            cs[(k4 + 1) * NT + n] = v.y;
            cs[(k4 + 2) * NT + n] = v.z;
            cs[(k4 + 3) * NT + n] = v.w;
        }
        if (tid < NT) {
            int gn = nbase + tid;
            c2s[tid] = (gn < cend) ? c2g[gn] : BIG;
        }
        __syncthreads();

        float acc[8][8];
#pragma unroll
        for (int i = 0; i < 8; ++i)
#pragma unroll
            for (int j = 0; j < 8; ++j) acc[i][j] = 0.f;

#pragma unroll 4
        for (int k = 0; k < DIM; ++k) {
            float4 xa = *(const float4*)(xs + k * MT + ty * 8);
            float4 xb = *(const float4*)(xs + k * MT + ty * 8 + 4);
            float4 ca = *(const float4*)(cs + k * NT + tx * 8);
            float4 cb = *(const float4*)(cs + k * NT + tx * 8 + 4);
            float xv[8] = {xa.x, xa.y, xa.z, xa.w, xb.x, xb.y, xb.z, xb.w};
            float cv[8] = {ca.x, ca.y, ca.z, ca.w, cb.x, cb.y, cb.z, cb.w};
#pragma unroll
            for (int i = 0; i < 8; ++i)
#pragma unroll
                for (int j = 0; j < 8; ++j)
                    acc[i][j] = fmaf(xv[i], cv[j], acc[i][j]);
        }

        // Running min of (c2 - 2*dot); x2 added later (constant per token,
        // order-preserving). Ascending j + ascending tiles + strict '<'
        // == first-occurrence argmin semantics.
#pragma unroll
        for (int j = 0; j < 8; ++j) {
            int n = tx * 8 + j;
            float c2v = c2s[n];
            int gn = nbase + n;
#pragma unroll
            for (int i = 0; i < 8; ++i) {
                float v = fmaf(-2.f, acc[i][j], c2v);
                if (v < bmin[i]) { bmin[i] = v; bidx[i] = gn; }
            }
        }
    }

    // Cross-tx reduction via LDS (reuse xs region; xs no longer needed).
    __syncthreads();
    float* red_f = smem;                       // [16][128]
    int*   red_i = (int*)(smem + 16 * MT);     // [16][128]
#pragma unroll
    for (int i = 0; i < 8; ++i) {
        red_f[tx * MT + ty * 8 + i] = bmin[i];
        red_i[tx * MT + ty * 8 + i] = bidx[i];
    }
    __syncthreads();
    if (tid < MT) {
        float bv = BIG;
        int bi = 0x7fffffff;
        for (int c = 0; c < 16; ++c) {
            float v = red_f[c * MT + tid];
            int id = red_i[c * MT + tid];
            // full comparator: bests come from different tiles, so tx order
            // is not index order — tie-break on smaller index.
            if (v < bv || (v == bv && id < bi)) { bv = v; bi = id; }
        }
        int gm = m0 + tid;
        bv += x2g[gm];  // full (unclamped) d2
        pmin[(size_t)chunk * NTOK + gm] = bv;
        pidx[(size_t)chunk * NTOK + gm] = bi;
    }
}

// ---------------------------------------------------------------------------
// Kernel 3: reduce 32 chunk partials per token, threshold, emit int ids.
// ---------------------------------------------------------------------------
__global__ void nn_stage2_kernel(const float* __restrict__ pmin,
                                 const int* __restrict__ pidx,
                                 int* __restrict__ out) {
    int t = blockIdx.x * 256 + threadIdx.x;
    if (t >= NTOK) return;
    float bv = BIG;
    int bi = 0x7fffffff;
    for (int c = 0; c < NCHUNK; ++c) {
        float v = pmin[(size_t)c * NTOK + t];
        int id = pidx[(size_t)c * NTOK + t];
        if (v < bv || (v == bv && id < bi)) { bv = v; bi = id; }
    }
    float d2 = fmaxf(bv, 0.f);  // match jnp.maximum(..., 0)
    out[t] = (d2 <= THRESH) ? bi : -1;
}

// ---------------------------------------------------------------------------
// Workspace layout (floats): c2[50048] | x2[2048] | pmin[32*2048] | pidx[32*2048]
// Total ~733 KB.
// ---------------------------------------------------------------------------
extern "C" void kernel_launch(void* const* d_in, const int* in_sizes, int n_in,
                              void* d_out, int out_size, void* d_ws, size_t ws_size,
                              hipStream_t stream) {
    const float* x     = (const float*)d_in[0];  // [2,1024,64]
    const float* codes = (const float*)d_in[1];  // [50000,64]

    float* c2   = (float*)d_ws;
    float* x2   = c2 + 50048;
    float* pmin = x2 + NTOK;
    int*   pidx = (int*)(pmin + (size_t)NCHUNK * NTOK);
    int*   out  = (int*)d_out;

    nn_norms_kernel<<<(NCODES + 255) / 256, 256, 0, stream>>>(x, codes, c2, x2);
    nn_stage1_kernel<<<dim3(16, NCHUNK), 256, 0, stream>>>(x, codes, c2, x2, pmin, pidx);
    nn_stage2_kernel<<<(NTOK + 255) / 256, 256, 0, stream>>>(pmin, pidx, out);
}

// Round 2
// 271.743 us; speedup vs baseline: 1.0004x; 1.0004x over previous
//
#include <hip/hip_runtime.h>

// Problem constants
#define NTOK   2048      // 2 * 1024 tokens
#define DIM    64
#define NCODES 50000
#define NCHUNK 32
#define CHUNK  1563      // ceil(50000/32)
#define MT     128       // token tile
#define NT     128       // code tile
#define TILES_PER_CHUNK 13  // ceil(1563/128)
#define THRESH 100.0f
#define BIG    3.0e38f

// ---------------------------------------------------------------------------
// Kernel 1: squared norms of codes (c2) and tokens (x2).
// ---------------------------------------------------------------------------
__global__ void nn_norms_kernel(const float* __restrict__ x,
                                const float* __restrict__ codes,
                                float* __restrict__ c2,
                                float* __restrict__ x2) {
    int gid = blockIdx.x * 256 + threadIdx.x;
    if (gid < NCODES) {
        const float4* p = (const float4*)(codes + (size_t)gid * DIM);
        float s = 0.f;
#pragma unroll
        for (int i = 0; i < DIM / 4; ++i) {
            float4 v = p[i];
            s = fmaf(v.x, v.x, s); s = fmaf(v.y, v.y, s);
            s = fmaf(v.z, v.z, s); s = fmaf(v.w, v.w, s);
        }
        c2[gid] = s;
    }
    if (gid < NTOK) {
        const float4* p = (const float4*)(x + (size_t)gid * DIM);
        float s = 0.f;
#pragma unroll
        for (int i = 0; i < DIM / 4; ++i) {
            float4 v = p[i];
            s = fmaf(v.x, v.x, s); s = fmaf(v.y, v.y, s);
            s = fmaf(v.z, v.z, s); s = fmaf(v.w, v.w, s);
        }
        x2[gid] = s;
    }
}

// ---------------------------------------------------------------------------
// Kernel 2: per (token-tile, code-chunk) partial argmin.
// Block = 256 threads as 16(tx: codes) x 16(ty: tokens), 8x8 micro-tile.
// LDS k-major: xs[k][m], cs[k][n].
//
// Bank-conflict design (the R0->R1 fix):
//  * staging: lane handles column n = g&127, rows k4..k4+3. Write bank =
//    n%32 -> each bank exactly 2x per wave -> free (2-way, m136).
//  * compute: thread's 8 columns are tx*4+{0..3} and 64+tx*4+{0..3}; each
//    float4 read has addresses strided 16B -> 2-way per bank -> free.
//  * next code tile is prefetched into registers during compute (latency
//    hidden across the barrier).
// ---------------------------------------------------------------------------
__global__ __launch_bounds__(256, 2)
void nn_stage1_kernel(const float* __restrict__ x,
                      const float* __restrict__ codes,
                      const float* __restrict__ c2g,
                      const float* __restrict__ x2g,
                      float* __restrict__ pmin,
                      int* __restrict__ pidx) {
    __shared__ float smem[DIM * MT + DIM * NT + NT];  // 66048 B
    float* xs  = smem;                    // [64][128] k-major
    float* cs  = smem + DIM * MT;         // [64][128] k-major
    float* c2s = smem + DIM * (MT + NT);  // [128]

    const int tid = threadIdx.x;
    const int tx = tid & 15;   // code column group
    const int ty = tid >> 4;   // token row group
    const int m0 = blockIdx.x * MT;
    const int chunk = blockIdx.y;
    const int cstart = chunk * CHUNK;
    const int cend = min(cstart + CHUNK, NCODES);

    // ---- stage x tile (once), conflict-free transpose ----
#pragma unroll
    for (int it = 0; it < 8; ++it) {
        int g = it * 256 + tid;
        int m = g & 127;
        int k4 = (g >> 7) << 2;
        float4 v = *(const float4*)(x + (size_t)(m0 + m) * DIM + k4);
        xs[(k4 + 0) * MT + m] = v.x;
        xs[(k4 + 1) * MT + m] = v.y;
        xs[(k4 + 2) * MT + m] = v.z;
        xs[(k4 + 3) * MT + m] = v.w;
    }

    float bmin[8];
    int   bidx[8];
#pragma unroll
    for (int i = 0; i < 8; ++i) { bmin[i] = BIG; bidx[i] = 0; }

    // register prefetch buffers for the code tile
    float4 pr[8];
    float  prc = BIG;

    auto load_tile = [&](int t) {
        const int nbase = cstart + t * NT;
#pragma unroll
        for (int it = 0; it < 8; ++it) {
            int g = it * 256 + tid;
            int n = g & 127;
            int k4 = (g >> 7) << 2;
            int gn = nbase + n;
            pr[it] = (gn < cend)
                   ? *(const float4*)(codes + (size_t)gn * DIM + k4)
                   : make_float4(0.f, 0.f, 0.f, 0.f);
        }
        if (tid < NT) {
            int gn = nbase + tid;
            prc = (gn < cend) ? c2g[gn] : BIG;
        }
    };

    load_tile(0);

    for (int t = 0; t < TILES_PER_CHUNK; ++t) {
        const int nbase = cstart + t * NT;
        __syncthreads();  // previous tile's readers are done with cs/c2s

        // regs -> LDS (conflict-free: bank = n%32, 2 lanes/bank)
#pragma unroll
        for (int it = 0; it < 8; ++it) {
            int g = it * 256 + tid;
            int n = g & 127;
            int k4 = (g >> 7) << 2;
            cs[(k4 + 0) * NT + n] = pr[it].x;
            cs[(k4 + 1) * NT + n] = pr[it].y;
            cs[(k4 + 2) * NT + n] = pr[it].z;
            cs[(k4 + 3) * NT + n] = pr[it].w;
        }
        if (tid < NT) c2s[tid] = prc;

        // issue next tile's global loads; latency hides under compute
        if (t + 1 < TILES_PER_CHUNK) load_tile(t + 1);

        __syncthreads();

        float acc[8][8];
#pragma unroll
        for (int i = 0; i < 8; ++i)
#pragma unroll
            for (int j = 0; j < 8; ++j) acc[i][j] = 0.f;

#pragma unroll 8
        for (int k = 0; k < DIM; ++k) {
            float4 xa = *(const float4*)(xs + k * MT + ty * 4);
            float4 xb = *(const float4*)(xs + k * MT + 64 + ty * 4);
            float4 ca = *(const float4*)(cs + k * NT + tx * 4);
            float4 cb = *(const float4*)(cs + k * NT + 64 + tx * 4);
            float xv[8] = {xa.x, xa.y, xa.z, xa.w, xb.x, xb.y, xb.z, xb.w};
            float cv[8] = {ca.x, ca.y, ca.z, ca.w, cb.x, cb.y, cb.z, cb.w};
#pragma unroll
            for (int i = 0; i < 8; ++i)
#pragma unroll
                for (int j = 0; j < 8; ++j)
                    acc[i][j] = fmaf(xv[i], cv[j], acc[i][j]);
        }

        // running argmin of (c2 - 2*dot); x2 added at the end (constant per
        // token, order-preserving). (v,id) lexicographic comparator ==
        // first-occurrence argmin.
#pragma unroll
        for (int j = 0; j < 8; ++j) {
            int n = tx * 4 + (j & 3) + ((j >> 2) << 6);
            float c2v = c2s[n];
            int gn = nbase + n;
#pragma unroll
            for (int i = 0; i < 8; ++i) {
                float v = fmaf(-2.f, acc[i][j], c2v);
                if (v < bmin[i] || (v == bmin[i] && gn < bidx[i])) {
                    bmin[i] = v; bidx[i] = gn;
                }
            }
        }
    }

    // ---- cross-tx reduction via LDS (reuse xs region) ----
    __syncthreads();
    float* red_f = smem;                   // [16][128]
    int*   red_i = (int*)(smem + 16 * MT); // [16][128]
#pragma unroll
    for (int i = 0; i < 8; ++i) {
        int m = ty * 4 + (i & 3) + ((i >> 2) << 6);
        red_f[tx * MT + m] = bmin[i];
        red_i[tx * MT + m] = bidx[i];
    }
    __syncthreads();
    if (tid < MT) {
        float bv = BIG;
        int bi = 0x7fffffff;
        for (int c = 0; c < 16; ++c) {
            float v = red_f[c * MT + tid];
            int id = red_i[c * MT + tid];
            if (v < bv || (v == bv && id < bi)) { bv = v; bi = id; }
        }
        int gm = m0 + tid;
        bv += x2g[gm];  // full (unclamped) d2
        pmin[(size_t)chunk * NTOK + gm] = bv;
        pidx[(size_t)chunk * NTOK + gm] = bi;
    }
}

// ---------------------------------------------------------------------------
// Kernel 3: reduce 32 chunk partials per token, threshold, emit int ids.
// ---------------------------------------------------------------------------
__global__ void nn_stage2_kernel(const float* __restrict__ pmin,
                                 const int* __restrict__ pidx,
                                 int* __restrict__ out) {
    int t = blockIdx.x * 256 + threadIdx.x;
    if (t >= NTOK) return;
    float bv = BIG;
    int bi = 0x7fffffff;
    for (int c = 0; c < NCHUNK; ++c) {
        float v = pmin[(size_t)c * NTOK + t];
        int id = pidx[(size_t)c * NTOK + t];
        if (v < bv || (v == bv && id < bi)) { bv = v; bi = id; }
    }
    float d2 = fmaxf(bv, 0.f);  // match jnp.maximum(..., 0)
    out[t] = (d2 <= THRESH) ? bi : -1;
}

// ---------------------------------------------------------------------------
// Workspace layout (floats): c2[50048] | x2[2048] | pmin[32*2048] | pidx[32*2048]
// ---------------------------------------------------------------------------
extern "C" void kernel_launch(void* const* d_in, const int* in_sizes, int n_in,
                              void* d_out, int out_size, void* d_ws, size_t ws_size,
                              hipStream_t stream) {
    const float* x     = (const float*)d_in[0];  // [2,1024,64]
    const float* codes = (const float*)d_in[1];  // [50000,64]

    float* c2   = (float*)d_ws;
    float* x2   = c2 + 50048;
    float* pmin = x2 + NTOK;
    int*   pidx = (int*)(pmin + (size_t)NCHUNK * NTOK);
    int*   out  = (int*)d_out;

    nn_norms_kernel<<<(NCODES + 255) / 256, 256, 0, stream>>>(x, codes, c2, x2);
    nn_stage1_kernel<<<dim3(16, NCHUNK), 256, 0, stream>>>(x, codes, c2, x2, pmin, pidx);
    nn_stage2_kernel<<<(NTOK + 255) / 256, 256, 0, stream>>>(pmin, pidx, out);
}

// Round 3
// 231.747 us; speedup vs baseline: 1.1731x; 1.1726x over previous
//
#include <hip/hip_runtime.h>

// Problem constants
#define NTOK   2048
#define DIM    64
#define NCODES 50000
#define THRESH 100.0f
#define BIG    3.0e38f
#define MARGIN 6.0f      // >= 2*E, E = bf16 dot error bound (~1.6); 2x safety

#define NBLK   392       // per-128-code blocks: ceil(50000/128) rounded to tile grid (196 tiles * 2)
#define CTILES 196       // stage A code tiles of 256

typedef __attribute__((ext_vector_type(8)))  __bf16 bf16x8;
typedef __attribute__((ext_vector_type(16))) float  float16;

// fp32 -> bf16 RNE (bit pattern)
__device__ __forceinline__ unsigned short f2bf(float f) {
    union { float f; unsigned int u; } v; v.f = f;
    unsigned int r = v.u + 0x7FFF + ((v.u >> 16) & 1);
    return (unsigned short)(r >> 16);
}
__device__ __forceinline__ unsigned int pack2(float a, float b) {
    return (unsigned int)f2bf(a) | ((unsigned int)f2bf(b) << 16);
}

// ---------------------------------------------------------------------------
// Kernel 1: squared norms (fp32, fmaf chain — same association as rescore)
// ---------------------------------------------------------------------------
__global__ void nn_norms_kernel(const float* __restrict__ x,
                                const float* __restrict__ codes,
                                float* __restrict__ c2,
                                float* __restrict__ x2) {
    int gid = blockIdx.x * 256 + threadIdx.x;
    if (gid < NCODES) {
        const float4* p = (const float4*)(codes + (size_t)gid * DIM);
        float s = 0.f;
#pragma unroll
        for (int i = 0; i < DIM / 4; ++i) {
            float4 v = p[i];
            s = fmaf(v.x, v.x, s); s = fmaf(v.y, v.y, s);
            s = fmaf(v.z, v.z, s); s = fmaf(v.w, v.w, s);
        }
        c2[gid] = s;
    }
    if (gid < NTOK) {
        const float4* p = (const float4*)(x + (size_t)gid * DIM);
        float s = 0.f;
#pragma unroll
        for (int i = 0; i < DIM / 4; ++i) {
            float4 v = p[i];
            s = fmaf(v.x, v.x, s); s = fmaf(v.y, v.y, s);
            s = fmaf(v.z, v.z, s); s = fmaf(v.w, v.w, s);
        }
        x2[gid] = s;
    }
}

// ---------------------------------------------------------------------------
// Kernel 2 (stage A): bf16 MFMA screening.
// Grid: (16 token-tiles of 128) x (196 code-tiles of 256). WG = 256 = 4 waves.
// Wave (wc = w&1, wt = w>>1): codes wc*128+[0,128), tokens wt*64+[0,64).
// MFMA 32x32x16_bf16, A = codes (M), B = tokens (N), acc initialized to
// -c2/2 so D = dot - c2/2 and per-token blockmin = -2 * max(D).
// LDS rows padded to 72 bf16 (144B) -> frag ds_read_b128 conflict pattern
// equals the stride-1 baseline (conflict-free).
// ---------------------------------------------------------------------------
__global__ __launch_bounds__(256, 2)
void nn_stageA_kernel(const float* __restrict__ x,
                      const float* __restrict__ codes,
                      const float* __restrict__ c2g,
                      float* __restrict__ blockmin) {
    __shared__ __bf16 cs[256 * 72];   // codes tile, row-major, 144B stride
    __shared__ __bf16 xs[128 * 72];   // token tile
    __shared__ float  c2s[256];

    const int tid  = threadIdx.x;
    const int w    = tid >> 6;
    const int lane = tid & 63;
    const int l31  = lane & 31;
    const int h    = lane >> 5;       // k-octet selector
    const int wc   = w & 1;           // code half (128 codes)
    const int wt   = w >> 1;          // token half (64 tokens)
    const int t0   = blockIdx.x * 128;
    const int n0   = blockIdx.y * 256;

    // ---- stage codes tile (256 rows x 64 fp32 -> bf16), coalesced ----
#pragma unroll
    for (int it = 0; it < 16; ++it) {
        int g = it * 256 + tid;
        int row = g >> 4;
        int c4 = (g & 15) * 4;
        int n = n0 + row;
        float4 v = make_float4(0.f, 0.f, 0.f, 0.f);
        if (n < NCODES) v = *(const float4*)(codes + (size_t)n * DIM + c4);
        uint2 p; p.x = pack2(v.x, v.y); p.y = pack2(v.z, v.w);
        *(uint2*)&cs[row * 72 + c4] = p;
    }
    // ---- stage token tile (128 x 64) ----
#pragma unroll
    for (int it = 0; it < 8; ++it) {
        int g = it * 256 + tid;
        int row = g >> 4;
        int c4 = (g & 15) * 4;
        float4 v = *(const float4*)(x + (size_t)(t0 + row) * DIM + c4);
        uint2 p; p.x = pack2(v.x, v.y); p.y = pack2(v.z, v.w);
        *(uint2*)&xs[row * 72 + c4] = p;
    }
    {
        int n = n0 + tid;
        c2s[tid] = (n < NCODES) ? c2g[n] : BIG;
    }
    __syncthreads();

    // ---- init acc[mi][nj][r] = -c2[code_row]/2 ----
    // C/D: col = lane&31 (token), row = (r&3) + 8*(r>>2) + 4*h (code)
    float16 acc[4][2];
#pragma unroll
    for (int mi = 0; mi < 4; ++mi) {
#pragma unroll
        for (int g2 = 0; g2 < 4; ++g2) {
            float4 c4 = *(float4*)&c2s[wc * 128 + mi * 32 + g2 * 8 + 4 * h];
#pragma unroll
            for (int i = 0; i < 4; ++i) {
                float iv = -0.5f * ((float*)&c4)[i];
                acc[mi][0][g2 * 4 + i] = iv;
                acc[mi][1][g2 * 4 + i] = iv;
            }
        }
    }

    // ---- MFMA main: K = 64 in 4 steps of 16 ----
#pragma unroll
    for (int s = 0; s < 4; ++s) {
        bf16x8 a[4], b[2];
#pragma unroll
        for (int mi = 0; mi < 4; ++mi)
            a[mi] = *(bf16x8*)&cs[(wc * 128 + mi * 32 + l31) * 72 + s * 16 + h * 8];
#pragma unroll
        for (int nj = 0; nj < 2; ++nj)
            b[nj] = *(bf16x8*)&xs[(wt * 64 + nj * 32 + l31) * 72 + s * 16 + h * 8];
#pragma unroll
        for (int mi = 0; mi < 4; ++mi)
#pragma unroll
            for (int nj = 0; nj < 2; ++nj)
                acc[mi][nj] = __builtin_amdgcn_mfma_f32_32x32x16_bf16(
                    a[mi], b[nj], acc[mi][nj], 0, 0, 0);
    }

    // ---- epilogue: per-token max(D) over this wave's 128 codes ----
#pragma unroll
    for (int nj = 0; nj < 2; ++nj) {
        float m = acc[0][nj][0];
#pragma unroll
        for (int mi = 0; mi < 4; ++mi)
#pragma unroll
            for (int r = 0; r < 16; ++r)
                m = fmaxf(m, acc[mi][nj][r]);
        // fold the lane^32 half (covers code rows +4)
        m = fmaxf(m, __shfl_xor(m, 32));
        if (lane < 32) {
            int token = t0 + wt * 64 + nj * 32 + lane;
            blockmin[(size_t)token * NBLK + blockIdx.y * 2 + wc] = -2.0f * m;
        }
    }
}

// ---------------------------------------------------------------------------
// Kernel 3 (finalize): per token — gmin over 392 blockmins, exact fp32
// rescore of candidate blocks (blockmin <= gmin + MARGIN), threshold, emit id.
// One wave per token; no atomics.
// ---------------------------------------------------------------------------
__global__ __launch_bounds__(256)
void nn_finalize_kernel(const float* __restrict__ x,
                        const float* __restrict__ codes,
                        const float* __restrict__ c2,
                        const float* __restrict__ x2,
                        const float* __restrict__ blockmin,
                        int* __restrict__ out) {
    const int tid  = threadIdx.x;
    const int w    = tid >> 6;
    const int lane = tid & 63;
    const int t    = blockIdx.x * 4 + w;

    // preload x[t] (broadcast loads, cache-served)
    float4 xr[16];
#pragma unroll
    for (int q = 0; q < 16; ++q)
        xr[q] = *(const float4*)(x + (size_t)t * DIM + q * 4);
    const float x2v = x2[t];

    // global approx min over blocks
    float g = BIG;
#pragma unroll
    for (int i = 0; i < 7; ++i) {
        int b = i * 64 + lane;
        if (b < NBLK) g = fminf(g, blockmin[(size_t)t * NBLK + b]);
    }
#pragma unroll
    for (int m = 1; m < 64; m <<= 1) g = fminf(g, __shfl_xor(g, m));
    const float thresh = g + MARGIN;

    float bv = BIG;
    int   bi = 0x7fffffff;
#pragma unroll 1
    for (int i = 0; i < 7; ++i) {
        int b = i * 64 + lane;
        float bm = (b < NBLK) ? blockmin[(size_t)t * NBLK + b] : BIG;
        unsigned long long mask = __ballot(bm <= thresh);
        while (mask) {
            int sl = __ffsll((unsigned long long)mask) - 1;
            mask &= mask - 1;
            int blk = i * 64 + sl;
            int nbase = blk * 128;
#pragma unroll
            for (int rep = 0; rep < 2; ++rep) {
                int n = nbase + rep * 64 + lane;
                if (n < NCODES) {
                    const float4* cp = (const float4*)(codes + (size_t)n * DIM);
                    float dot = 0.f;
#pragma unroll
                    for (int q = 0; q < 16; ++q) {
                        float4 c4 = cp[q];
                        dot = fmaf(xr[q].x, c4.x, dot);
                        dot = fmaf(xr[q].y, c4.y, dot);
                        dot = fmaf(xr[q].z, c4.z, dot);
                        dot = fmaf(xr[q].w, c4.w, dot);
                    }
                    float d2 = fmaxf(fmaf(-2.f, dot, x2v + c2[n]), 0.f);
                    if (d2 < bv || (d2 == bv && n < bi)) { bv = d2; bi = n; }
                }
            }
        }
    }
    // wave reduce (v, id) — first-occurrence comparator
#pragma unroll
    for (int m = 1; m < 64; m <<= 1) {
        float vv = __shfl_xor(bv, m);
        int   ii = __shfl_xor(bi, m);
        if (vv < bv || (vv == bv && ii < bi)) { bv = vv; bi = ii; }
    }
    if (lane == 0) out[t] = (bv <= THRESH) ? bi : -1;
}

// ---------------------------------------------------------------------------
// Workspace: c2[50048] | x2[2048] | blockmin[2048*392]  (~3.4 MB)
// ---------------------------------------------------------------------------
extern "C" void kernel_launch(void* const* d_in, const int* in_sizes, int n_in,
                              void* d_out, int out_size, void* d_ws, size_t ws_size,
                              hipStream_t stream) {
    const float* x     = (const float*)d_in[0];  // [2,1024,64]
    const float* codes = (const float*)d_in[1];  // [50000,64]

    float* c2       = (float*)d_ws;
    float* x2       = c2 + 50048;
    float* blockmin = x2 + NTOK;
    int*   out      = (int*)d_out;

    nn_norms_kernel<<<196, 256, 0, stream>>>(x, codes, c2, x2);
    nn_stageA_kernel<<<dim3(16, CTILES), 256, 0, stream>>>(x, codes, c2, blockmin);
    nn_finalize_kernel<<<NTOK / 4, 256, 0, stream>>>(x, codes, c2, x2, blockmin, out);
}